// Round 8
// baseline (545.999 us; speedup 1.0000x reference)
//
#include <hip/hip_runtime.h>

// NestLinearQuantizer: out = quant(x) @ dequant(packed)^T + bias
// Exact int8 factorization: out[t,o] = as*scale[o]*(dot_i8[t,o] - zp[o]*rowsum[t]) + bias[o]
//   q[o,i] = max(hi_nibble*16 + (packed_low - 144), -128)   (exact int8)
//   xi8    = clip(rint(x/as), -128, 127)
//
// Block = M=128 x N=16, 4 waves m-split (32 rows each) -> grid 1024 = 4 blocks/CU.
// Per 256-k iteration: each wave loads+unpacks its own k-quarter of B into a
// double-buffered LDS slab (one lgkm-only barrier), then all waves read B-frags
// and MFMA with L2-hot fragment-packed A. Packed-B prefetch = named regs with
// depth-2 flight, pinned above the barrier by an empty memory-clobber asm.

typedef int v4i __attribute__((ext_vector_type(4)));

#define TOKENS 256
#define INF 8192
#define OUTF 8192
#define KSTEP 256
#define NITER 32   // 8192 / 256

// ---------------- Kernel 1: quantize x -> int8 in MFMA-fragment layout + rowsum ----
// apk word index: kb*4096 + f*256 + lane*4 + j  <=>
//   xi8[row = f*16 + (lane&15)][k = kb*64 + (lane>>4)*16 + j*4 + byte]
__global__ __launch_bounds__(256) void quant_x_kernel(
    const float* __restrict__ x, const float* __restrict__ act_scale,
    int* __restrict__ apk, int* __restrict__ rowsum)
{
    const int t = blockIdx.x;
    const int j = threadIdx.x;
    const float s = act_scale[0];
    const float4* xrow = (const float4*)(x + (size_t)t * INF);
    const int f    = t >> 4;
    const int llow = t & 15;
    int lsum = 0;
#pragma unroll
    for (int c = 0; c < 8; ++c) {
        const int kw = j + c * 256;
        float4 v = xrow[kw];
        int q0 = (int)rintf(v.x / s); q0 = q0 < -128 ? -128 : (q0 > 127 ? 127 : q0);
        int q1 = (int)rintf(v.y / s); q1 = q1 < -128 ? -128 : (q1 > 127 ? 127 : q1);
        int q2 = (int)rintf(v.z / s); q2 = q2 < -128 ? -128 : (q2 > 127 ? 127 : q2);
        int q3 = (int)rintf(v.w / s); q3 = q3 < -128 ? -128 : (q3 > 127 ? 127 : q3);
        const int word = (q0 & 255) | ((q1 & 255) << 8) | ((q2 & 255) << 16) | ((q3 & 255) << 24);
        const int k0 = kw << 2;
        const int kb = k0 >> 6;
        const int ks = k0 & 63;
        const int lane = ((ks >> 4) << 4) + llow;
        apk[kb * 4096 + f * 256 + (lane << 2) + ((ks & 15) >> 2)] = word;
        lsum += q0 + q1 + q2 + q3;
    }
#pragma unroll
    for (int off = 32; off > 0; off >>= 1) lsum += __shfl_down(lsum, off, 64);
    __shared__ int wsum[4];
    if ((j & 63) == 0) wsum[j >> 6] = lsum;
    __syncthreads();
    if (j == 0) rowsum[t] = wsum[0] + wsum[1] + wsum[2] + wsum[3];
}

// ---------------- Kernel 2: pipelined unpack->LDS + int8 MFMA GEMM -----------------
__device__ __forceinline__ int unpack4(v4i pl, int pha, int phb) {
    // q = max(nib*16 + pl - 144, -128); pha covers k{0,1}, phb k{2,3} (hi nib = even k)
    int q0 = (pha & 0xF0)        + pl[0] - 144; q0 = q0 < -128 ? -128 : q0;
    int q1 = ((pha & 0x0F) << 4) + pl[1] - 144; q1 = q1 < -128 ? -128 : q1;
    int q2 = (phb & 0xF0)        + pl[2] - 144; q2 = q2 < -128 ? -128 : q2;
    int q3 = ((phb & 0x0F) << 4) + pl[3] - 144; q3 = q3 < -128 ? -128 : q3;
    return (q0 & 255) | ((q1 & 255) << 8) | ((q2 & 255) << 16) | ((q3 & 255) << 24);
}

__global__ __launch_bounds__(256, 4) void gemm_kernel(
    const int* __restrict__ apk, const int* __restrict__ rowsum,
    const int* __restrict__ packed_high, const int* __restrict__ packed_low,
    const float* __restrict__ scale, const float* __restrict__ zero_point,
    const float* __restrict__ bias, const float* __restrict__ act_scale,
    float* __restrict__ out)
{
    // unpacked B slab: [buf][slot 16][col 16][16B]; slot s covers k = s*16..s*16+15
    __shared__ __align__(16) signed char Bu[2][4096];

    const int tid  = threadIdx.x;
    const int lane = tid & 63;
    const int w    = tid >> 6;
    const int bid  = blockIdx.x;
    const int H    = bid >> 9;           // m-half (twin blocks p, p+512 share B & XCD)
    const int n0   = (bid & 511) << 4;
    const int c    = lane & 15;
    const int kq   = lane >> 4;
    const int o    = n0 + c;

    // unpack share: this lane owns col c, k in [t*256 + w*64 + kq*16, +16)
    const int ksh = (w << 6) + (kq << 4);
    const int* pl_p = packed_low  + (size_t)o * INF       + ksh;
    const int* ph_p = packed_high + (size_t)o * (INF / 2) + (ksh >> 1);
    const int wof = ((w << 2) + kq) * 256 + (c << 4);   // LDS write: slot w*4+kq
    const int rof = (kq << 8) + (c << 4);               // LDS read:  + s*1024

    // A fragments f0 = H*8 + w*2, f0+1 (rows f*16..f*16+15)
    const int* a_p = apk + (((H << 3) + (w << 1)) << 8) + (lane << 2);

    v4i acc0 = {0,0,0,0}, acc1 = {0,0,0,0};
    v4i plP[4], phP[2], plQ[4], phQ[2];

#define LOADPK(PL, PH, T) {                                                     \
        const int kk_ = ((T) & (NITER - 1)) * KSTEP;                            \
        _Pragma("unroll")                                                       \
        for (int m = 0; m < 4; ++m) PL[m] = *(const v4i*)(pl_p + kk_ + 4 * m);  \
        _Pragma("unroll")                                                       \
        for (int m = 0; m < 2; ++m) PH[m] = *(const v4i*)(ph_p + (kk_ >> 1) + 4 * m); }

#define HALF(PL, PH, BUF, T) {                                                        \
        v4i u;                                                                        \
        u[0] = unpack4(PL[0], PH[0][0], PH[0][1]);                                    \
        u[1] = unpack4(PL[1], PH[0][2], PH[0][3]);                                    \
        u[2] = unpack4(PL[2], PH[1][0], PH[1][1]);                                    \
        u[3] = unpack4(PL[3], PH[1][2], PH[1][3]);                                    \
        *(v4i*)(&Bu[BUF][wof]) = u;                                                   \
        /* A loads first (L2-hot, needed this iter) ... */                            \
        const int kb_ = (T) << 2;                                                     \
        v4i a0 = *(const v4i*)(a_p + (kb_ + 0) * 4096);                               \
        v4i a1 = *(const v4i*)(a_p + (kb_ + 0) * 4096 + 256);                         \
        v4i a2 = *(const v4i*)(a_p + (kb_ + 1) * 4096);                               \
        v4i a3 = *(const v4i*)(a_p + (kb_ + 1) * 4096 + 256);                         \
        v4i a4 = *(const v4i*)(a_p + (kb_ + 2) * 4096);                               \
        v4i a5 = *(const v4i*)(a_p + (kb_ + 2) * 4096 + 256);                         \
        v4i a6 = *(const v4i*)(a_p + (kb_ + 3) * 4096);                               \
        v4i a7 = *(const v4i*)(a_p + (kb_ + 3) * 4096 + 256);                         \
        /* ... then packed-B prefetch for T+2 (stays in flight across waits) */       \
        LOADPK(PL, PH, (T) + 2);                                                      \
        asm volatile("" ::: "memory");    /* pin all issues above the barrier */      \
        asm volatile("s_waitcnt lgkmcnt(0)" ::: "memory"); /* my ds_write done */     \
        __builtin_amdgcn_s_barrier();                                                 \
        v4i b0 = *(const v4i*)(&Bu[BUF][rof]);                                        \
        v4i b1 = *(const v4i*)(&Bu[BUF][1024 + rof]);                                 \
        v4i b2 = *(const v4i*)(&Bu[BUF][2048 + rof]);                                 \
        v4i b3 = *(const v4i*)(&Bu[BUF][3072 + rof]);                                 \
        acc0 = __builtin_amdgcn_mfma_i32_16x16x64_i8(a0, b0, acc0, 0, 0, 0);          \
        acc1 = __builtin_amdgcn_mfma_i32_16x16x64_i8(a1, b0, acc1, 0, 0, 0);          \
        acc0 = __builtin_amdgcn_mfma_i32_16x16x64_i8(a2, b1, acc0, 0, 0, 0);          \
        acc1 = __builtin_amdgcn_mfma_i32_16x16x64_i8(a3, b1, acc1, 0, 0, 0);          \
        acc0 = __builtin_amdgcn_mfma_i32_16x16x64_i8(a4, b2, acc0, 0, 0, 0);          \
        acc1 = __builtin_amdgcn_mfma_i32_16x16x64_i8(a5, b2, acc1, 0, 0, 0);          \
        acc0 = __builtin_amdgcn_mfma_i32_16x16x64_i8(a6, b3, acc0, 0, 0, 0);          \
        acc1 = __builtin_amdgcn_mfma_i32_16x16x64_i8(a7, b3, acc1, 0, 0, 0); }

    LOADPK(plP, phP, 0);
    LOADPK(plQ, phQ, 1);
    for (int t = 0; t < NITER; t += 2) {
        HALF(plP, phP, 0, t);
        HALF(plQ, phQ, 1, t + 1);
    }
#undef HALF
#undef LOADPK

    // --- epilogue: D layout col = lane&15, row = kq*4 + r within each 16-row frag ---
    const float as = act_scale[0];
    const float sc = as * scale[o];
    const float zo = zero_point[o];
    const float bo = bias[o];
    const int f0 = (H << 3) + (w << 1);
#pragma unroll
    for (int r = 0; r < 4; ++r) {
        const int t0 = f0 * 16 + (kq << 2) + r;
        const int t1 = t0 + 16;
        out[(size_t)t0 * OUTF + o] = fmaf(sc, (float)acc0[r] - zo * (float)rowsum[t0], bo);
        out[(size_t)t1 * OUTF + o] = fmaf(sc, (float)acc1[r] - zo * (float)rowsum[t1], bo);
    }
}

extern "C" void kernel_launch(void* const* d_in, const int* in_sizes, int n_in,
                              void* d_out, int out_size, void* d_ws, size_t ws_size,
                              hipStream_t stream)
{
    const float* x           = (const float*)d_in[0];
    const int*   packed_high = (const int*)d_in[1];
    const int*   packed_low  = (const int*)d_in[2];
    const float* scale       = (const float*)d_in[3];
    const float* zero_point  = (const float*)d_in[4];
    const float* bias        = (const float*)d_in[5];
    const float* act_scale   = (const float*)d_in[6];
    float* out = (float*)d_out;

    int* apk    = (int*)d_ws;                                  // 2 MB fragment-packed xi8
    int* rowsum = (int*)((char*)d_ws + (size_t)TOKENS * INF);  // 1 KB

    quant_x_kernel<<<TOKENS, 256, 0, stream>>>(x, act_scale, apk, rowsum);
    gemm_kernel<<<1024, 256, 0, stream>>>(apk, rowsum, packed_high, packed_low,
                                          scale, zero_point, bias, act_scale, out);
}